// Round 1
// baseline (187.291 us; speedup 1.0000x reference)
//
#include <hip/hip_runtime.h>

// GCN layer: H = X @ W^T ; out = A_coo @ H     (N=50000, E=1600000, F=128)
//
// Pipeline: memset(6.6KB counters)
//        -> fused 1024-thr kernel: MFMA gemm blocks (256 rows each, W staged
//           once in LDS, X global->reg) interleaved 1:1 with edge-partition
//           blocks (64-row bins, 4B entries, 8192 edges/block) — independent
//           work, fully co-resident (392 blocks = 24.5 waves/CU)
//        -> binned SpMM, feature-sharded: 4 blocks per bin, each owning a
//           32-feature quarter, pinned to an XCD pair via blockIdx%8 so each
//           XCD's gather working set (3.2MB Hb quarter) fits its 4MB L2.
//           Counting sort into LDS, register accumulation (8 waves x 8 rows,
//           4 edge-slots x 16 lanes per wave), nontemporal out stores.

constexpr int N_NODES = 50000;
constexpr int N_EDGES = 1600000;
constexpr int FEAT    = 128;

constexpr int ROWS_PER_BIN = 64;                                   // bin = row >> 6
constexpr int NB           = (N_NODES + ROWS_PER_BIN - 1) / ROWS_PER_BIN;  // 782
constexpr int CAP          = 2560;   // mean 2046, sd ~45 -> 11 sigma headroom
constexpr int CHUNK        = 8192;   // edges per partition block
constexpr int EPT          = 8;      // edges per thread (1024 thr)
constexpr int PART_BLOCKS  = (N_EDGES + CHUNK - 1) / CHUNK;        // 196
constexpr int GEMM_BLOCKS  = (N_NODES + 255) / 256;                // 196
constexpr int FUSED_BLOCKS = PART_BLOCKS + GEMM_BLOCKS;            // 392, pairs {part,gemm}
constexpr int OVF_CAP      = 8192;

// MFMA gemm LDS pitch (bf16 elems)
constexpr int PITCH = 136;

typedef short short8 __attribute__((ext_vector_type(8)));
typedef float f32x4  __attribute__((ext_vector_type(4)));
typedef float f32x2  __attribute__((ext_vector_type(2)));

__device__ __forceinline__ unsigned short f2bf(float x) {
    unsigned u = __float_as_uint(x);
    u += 0x7fffu + ((u >> 16) & 1u);   // round to nearest even
    return (unsigned short)(u >> 16);
}
__device__ __forceinline__ float bf2f(unsigned short s) {
    return __uint_as_float(((unsigned)s) << 16);
}

// binbuf entry: (rl:6 [26:31] | col:16 [10:25] | valq:10 [0:9])
__device__ __forceinline__ float dec_val10(unsigned w) {
    return (float)(w & 1023u) * (1.0f / 1023.0f);
}

// ---------------------------------------------------------------------------
// GEMM body (1024 thr): Hb = bf16(X @ W^T) for rows [g*256, g*256+256).
// W staged once (fp32->bf16 LDS, 34.8KB); X fragments global->register.
// ---------------------------------------------------------------------------
__device__ void gemm_body(const float* __restrict__ X, const float* __restrict__ W,
                          unsigned short* __restrict__ Hb, int g,
                          unsigned short* Wsh) {
    const int tid  = threadIdx.x;
    const int row0 = g * 256;

    // stage full W: 128x128 fp32 -> bf16 (4 float4 per thread)
#pragma unroll
    for (int t = 0; t < 4; t++) {
        int idx = tid + 1024 * t;          // 4096 float4 total
        int r   = idx >> 5;
        int c4  = (idx & 31) << 2;
        const float4 v = *(const float4*)&W[r * FEAT + c4];
        unsigned lo = f2bf(v.x) | ((unsigned)f2bf(v.y) << 16);
        unsigned hi = f2bf(v.z) | ((unsigned)f2bf(v.w) << 16);
        *(uint2*)&Wsh[r * PITCH + c4] = make_uint2(lo, hi);
    }
    __syncthreads();

    const int w    = tid >> 6;             // 16 waves; wave w -> rows 16w..16w+16
    const int lane = tid & 63;
    const int n    = lane & 15;
    const int q    = lane >> 4;

    f32x4 acc[8];
#pragma unroll
    for (int t = 0; t < 8; t++) acc[t] = (f32x4){0.f, 0.f, 0.f, 0.f};

    int xrow = row0 + 16 * w + n;
    if (xrow >= N_NODES) xrow = N_NODES - 1;   // dup row; store is guarded
    const float* xp = X + (size_t)xrow * FEAT;

#pragma unroll
    for (int kt = 0; kt < 4; kt++) {
        const int ko = kt * 32 + q * 8;
        const float4 a0 = *(const float4*)&xp[ko];
        const float4 a1 = *(const float4*)&xp[ko + 4];
        short8 bfrag;
        bfrag[0] = (short)f2bf(a0.x); bfrag[1] = (short)f2bf(a0.y);
        bfrag[2] = (short)f2bf(a0.z); bfrag[3] = (short)f2bf(a0.w);
        bfrag[4] = (short)f2bf(a1.x); bfrag[5] = (short)f2bf(a1.y);
        bfrag[6] = (short)f2bf(a1.z); bfrag[7] = (short)f2bf(a1.w);
#pragma unroll
        for (int t = 0; t < 8; t++) {
            const short8 afrag = *(const short8*)&Wsh[(16 * t + n) * PITCH + ko];
            acc[t] = __builtin_amdgcn_mfma_f32_16x16x32_bf16(afrag, bfrag, acc[t], 0, 0, 0);
        }
    }

    const int grow = row0 + 16 * w + n;
    if (grow < N_NODES) {
#pragma unroll
        for (int t = 0; t < 8; t++) {
            ushort4 pk;
            pk.x = f2bf(acc[t][0]); pk.y = f2bf(acc[t][1]);
            pk.z = f2bf(acc[t][2]); pk.w = f2bf(acc[t][3]);
            *(ushort4*)&Hb[grow * FEAT + 16 * t + 4 * q] = pk;   // 8B packed
        }
    }
}

// ---------------------------------------------------------------------------
// Partition body (1024 thr): edges [g*CHUNK, ..) -> 64-row bins, 4B entries.
// Counting pass caches (row, word, rank) in regs; one global atomic per
// (block,bin); placement writes block-consecutive runs (~10.5 entries).
// ---------------------------------------------------------------------------
__device__ void partition_body(const int* __restrict__ rows, const int* __restrict__ cols,
                               const float* __restrict__ vals,
                               int* __restrict__ gcur, unsigned* __restrict__ binbuf,
                               int* __restrict__ ovf_cnt, int* __restrict__ ovf,
                               int g, int* smem) {
    int* hist  = smem;        // NB
    int* wbase = smem + NB;   // NB
    const int tid = threadIdx.x;
    const int e0  = g * CHUNK;

    for (int i = tid; i < NB; i += 1024) hist[i] = 0;
    __syncthreads();

    int      myrow[EPT], myrank[EPT];
    unsigned myword[EPT];
#pragma unroll
    for (int t = 0; t < EPT; t++) {
        int e = e0 + t * 1024 + tid;
        if (e < N_EDGES) {
            int r = rows[e];
            unsigned vq = (unsigned)__float2int_rn(vals[e] * 1023.0f);
            myrow[t]  = r;
            myword[t] = ((unsigned)(r & 63) << 26) | ((unsigned)cols[e] << 10) | vq;
            myrank[t] = atomicAdd(&hist[r >> 6], 1);
        } else {
            myrow[t] = -1; myword[t] = 0; myrank[t] = 0;
        }
    }
    __syncthreads();

    for (int i = tid; i < NB; i += 1024) {
        int c = hist[i];
        wbase[i] = (c > 0) ? atomicAdd(&gcur[i], c) : 0;
    }
    __syncthreads();

#pragma unroll
    for (int t = 0; t < EPT; t++) {
        int r = myrow[t];
        if (r < 0) continue;
        int b    = r >> 6;
        int rank = wbase[b] + myrank[t];
        if (rank < CAP) {
            binbuf[(size_t)b * CAP + rank] = myword[t];
        } else {
            int k = atomicAdd(ovf_cnt, 1);
            if (k < OVF_CAP) ovf[k] = e0 + t * 1024 + tid;
        }
    }
}

// Fused: pairs of blocks -> {partition, gemm}. Both kinds co-resident from the
// first dispatch wave (392 blocks <= capacity); MFMA-bound gemm overlaps
// latency-bound partition.
__global__ __launch_bounds__(1024) void gemm_partition(
    const float* __restrict__ X, const float* __restrict__ W,
    unsigned short* __restrict__ Hb,
    const int* __restrict__ rows, const int* __restrict__ cols,
    const float* __restrict__ vals,
    int* __restrict__ gcur, unsigned* __restrict__ binbuf,
    int* __restrict__ ovf_cnt, int* __restrict__ ovf) {
    __shared__ unsigned short Wsh[128 * PITCH];   // 34.8KB; partition uses 6.3KB of it
    const int grp = blockIdx.x >> 1;
    if (blockIdx.x & 1) {
        gemm_body(X, W, Hb, grp, Wsh);
    } else {
        if (grp < PART_BLOCKS)
            partition_body(rows, cols, vals, gcur, binbuf, ovf_cnt, ovf, grp, (int*)Wsh);
    }
}

// ---------------------------------------------------------------------------
// Binned SpMM, feature-sharded: 4 blocks per bin, quarter q handles features
// [32q, 32q+32). Grid = 782*4 = 391*8; q = (bid&7)>>1 so each quarter's blocks
// land on one XCD pair (round-robin bid%8 -> XCD) and its 3.2MB Hb slice fits
// the 4MB per-XCD L2. Per wave: 4 edge-slots x 16 lanes (ushort2/lane = 64B
// gather per edge), cross-slot shfl_xor butterfly at row end. Out stores are
// nontemporal so 25.6MB of writes don't evict the hot Hb quarter.
// ---------------------------------------------------------------------------
__global__ __launch_bounds__(512) void spmm_bins(
    const int* __restrict__ gcur, const unsigned* __restrict__ binbuf,
    const unsigned short* __restrict__ Hb, float* __restrict__ out) {
    __shared__ unsigned sorted[CAP];          // 10.24KB
    __shared__ int hist[ROWS_PER_BIN];
    __shared__ int cnt_of[ROWS_PER_BIN];
    __shared__ int cur[ROWS_PER_BIN];

    const int bid  = blockIdx.x;
    const int q    = (bid & 7) >> 1;              // feature quarter (XCD-paired)
    const int b    = (bid >> 3) * 2 + (bid & 1);  // bin index, 0..781
    const int tid  = threadIdx.x;
    const int lane = tid & 63;
    const int w    = tid >> 6;                    // 8 waves

    if (tid < ROWS_PER_BIN) { hist[tid] = 0; cur[tid] = 0; }
    __syncthreads();

    int cnt = gcur[b];
    if (cnt > CAP) cnt = CAP;
    const unsigned* bb = binbuf + (size_t)b * CAP;

    // pass 1: count per row
    for (int i = tid; i < cnt; i += 512)
        atomicAdd(&hist[bb[i] >> 26], 1);
    __syncthreads();

    // exclusive scan of 64 counts (wave 0)
    if (w == 0) {
        int c = hist[lane];
        cnt_of[lane] = c;
        int v = c;
#pragma unroll
        for (int off = 1; off < 64; off <<= 1) {
            int u = __shfl_up(v, off);
            if (lane >= off) v += u;
        }
        hist[lane] = v - c;   // exclusive start
    }
    __syncthreads();

    // pass 2: scatter into row-sorted LDS, repacking to (bf16val:16 | col:16)
    for (int i = tid; i < cnt; i += 512) {
        unsigned m = bb[i];                   // L2-hot re-read
        int rl  = (int)(m >> 26);
        int pos = hist[rl] + atomicAdd(&cur[rl], 1);
        unsigned col = (m >> 10) & 0xffffu;
        unsigned vb  = (unsigned)f2bf(dec_val10(m));
        sorted[pos] = (vb << 16) | col;
    }
    __syncthreads();

    // register accumulation; wave w owns rows [w*8, w*8+8); slot = edge lane-group
    const int row0   = b * ROWS_PER_BIN;
    const int slot   = lane >> 4;                 // 0..3, one edge per slot
    const int lane16 = lane & 15;                 // 2 feats (ushort2) per lane
    const ushort2* __restrict__ Hq = (const ushort2*)Hb + q * 16 + lane16;
    float2* out2 = (float2*)out;

    for (int rr = 0; rr < 8; rr++) {
        const int rl = w * 8 + rr;
        const int gr = row0 + rl;
        if (gr >= N_NODES) break;
        const int s = hist[rl];
        const int e = s + cnt_of[rl];

        float accx = 0.f, accy = 0.f;
        int i = s;
        for (; i + 16 <= e; i += 16) {            // 16 edges = 4 steps x 4 slots
            float   vv[4];
            ushort2 hh[4];
#pragma unroll
            for (int u = 0; u < 4; u++) {
                unsigned m = sorted[i + u * 4 + slot];   // 4-way LDS broadcast
                vv[u] = __uint_as_float(m & 0xffff0000u);
                hh[u] = Hq[(int)(m & 0xffffu) * 64];     // 64B/edge, L2-hot quarter
            }
#pragma unroll
            for (int u = 0; u < 4; u++) {
                accx += vv[u] * bf2f(hh[u].x);
                accy += vv[u] * bf2f(hh[u].y);
            }
        }
        for (; i < e; i += 4) {                   // masked 4-at-a-time tail
            int idx = i + slot;
            unsigned m = (idx < e) ? sorted[idx] : 0u;   // m=0 -> v=0, col=0
            float v2 = __uint_as_float(m & 0xffff0000u);
            ushort2 h2 = Hq[(int)(m & 0xffffu) * 64];
            accx += v2 * bf2f(h2.x);
            accy += v2 * bf2f(h2.y);
        }
        // reduce across the 4 edge-slots
        accx += __shfl_xor(accx, 16); accy += __shfl_xor(accy, 16);
        accx += __shfl_xor(accx, 32); accy += __shfl_xor(accy, 32);
        if (slot == 0) {
            f32x2 r; r[0] = accx; r[1] = accy;
            __builtin_nontemporal_store(r, (f32x2*)&out2[(size_t)gr * 64 + q * 16 + lane16]);
        }
    }
}

// Overflow fixup (expected 0 entries; exact-correctness net, full precision).
__global__ void fixup_ovf(const int* __restrict__ ovf_cnt, const int* __restrict__ ovf,
                          const int* __restrict__ rows, const int* __restrict__ cols,
                          const float* __restrict__ vals,
                          const unsigned short* __restrict__ Hb, float* __restrict__ out) {
    int n = *ovf_cnt;
    if (n > OVF_CAP) n = OVF_CAP;
    for (int k = blockIdx.x; k < n; k += gridDim.x) {
        int e = ovf[k];
        int r = rows[e], c = cols[e];
        float v = vals[e];
        for (int f = threadIdx.x; f < FEAT; f += blockDim.x)
            atomicAdd(&out[r * FEAT + f], v * bf2f(Hb[c * FEAT + f]));
    }
}

// Fallback (tiny ws): gemm-only + push with global atomics.
__global__ __launch_bounds__(1024) void gemm_only(
    const float* __restrict__ X, const float* __restrict__ W,
    unsigned short* __restrict__ Hb) {
    __shared__ unsigned short Wsh[128 * PITCH];
    gemm_body(X, W, Hb, blockIdx.x, Wsh);
}

__global__ __launch_bounds__(256) void spmm_push_atomic(
    const int* __restrict__ rows, const int* __restrict__ cols,
    const float* __restrict__ vals, const unsigned short* __restrict__ Hb,
    float* __restrict__ out) {
    const int e    = blockIdx.x * 4 + (threadIdx.x >> 6);
    const int lane = threadIdx.x & 63;
    if (e >= N_EDGES) return;
    int r = rows[e], c = cols[e];
    float v = vals[e];
    atomicAdd(&out[r * FEAT + lane],      v * bf2f(Hb[c * FEAT + lane]));
    atomicAdd(&out[r * FEAT + 64 + lane], v * bf2f(Hb[c * FEAT + 64 + lane]));
}

// ---------------------------------------------------------------------------
extern "C" void kernel_launch(void* const* d_in, const int* in_sizes, int n_in,
                              void* d_out, int out_size, void* d_ws, size_t ws_size,
                              hipStream_t stream) {
    const float* X      = (const float*)d_in[0];
    const float* W      = (const float*)d_in[1];
    const float* A_vals = (const float*)d_in[2];
    const int*   A_rows = (const int*)d_in[3];
    const int*   A_cols = (const int*)d_in[4];
    float* out = (float*)d_out;

    auto align256 = [](size_t x) { return (x + 255) & ~size_t(255); };
    char* ws = (char*)d_ws;

    size_t off = 0;
    size_t hb_off   = off; off += align256(size_t(N_NODES) * FEAT * 2);        // 12.8MB
    size_t gcur_off = off; off += align256(size_t(NB) * sizeof(int));
    size_t ovfc_off = off; off += 256;
    size_t ovf_off  = off; off += align256(size_t(OVF_CAP) * sizeof(int));
    size_t bin_off  = off; off += size_t(NB) * CAP * sizeof(unsigned);         // 8.0MB
    const size_t need = off;

    unsigned short* Hb = (unsigned short*)(ws + hb_off);

    if (ws_size >= need) {
        int*      gcur    = (int*)(ws + gcur_off);
        int*      ovf_cnt = (int*)(ws + ovfc_off);
        int*      ovf     = (int*)(ws + ovf_off);
        unsigned* binbuf  = (unsigned*)(ws + bin_off);

        // zero gcur + ovf_cnt (contiguous, ~6.6KB) before the fused kernel
        hipMemsetAsync(ws + gcur_off, 0, (ovfc_off - gcur_off) + 256, stream);
        gemm_partition<<<FUSED_BLOCKS, 1024, 0, stream>>>(X, W, Hb, A_rows, A_cols, A_vals,
                                                          gcur, binbuf, ovf_cnt, ovf);
        spmm_bins<<<NB * 4, 512, 0, stream>>>(gcur, binbuf, Hb, out);
        fixup_ovf<<<16, 256, 0, stream>>>(ovf_cnt, ovf, A_rows, A_cols, A_vals, Hb, out);
    } else {
        // Safety path: bf16 H + atomic push.
        gemm_only<<<GEMM_BLOCKS, 1024, 0, stream>>>(X, W, Hb);
        hipMemsetAsync(out, 0, size_t(N_NODES) * FEAT * sizeof(float), stream);
        spmm_push_atomic<<<(N_EDGES + 3) / 4, 256, 0, stream>>>(A_rows, A_cols, A_vals, Hb, out);
    }
}

// Round 7
// 168.365 us; speedup vs baseline: 1.1124x; 1.1124x over previous
//
#include <hip/hip_runtime.h>

// GCN layer: H = X @ W^T ; out = A_coo @ H     (N=50000, E=1600000, F=128)
//
// Pipeline (3 graph nodes — round-0 proven structure, fixup folded in):
//   memset(6.6KB counters)
//   -> fused 1024-thr kernel: MFMA gemm blocks (256 rows each, W staged
//      once in LDS, X global->reg) interleaved 1:2 with edge-partition
//      blocks (64-row bins, 4B entries) — independent work, co-resident
//   -> binned SpMM: one 512-thr block per bin, counting sort into LDS
//      with (bf16val|col) repack, register accumulation (8 waves x 8
//      rows), in-register overflow fixup (expected empty), nontemporal
//      output stores. No fp atomics in hot paths.
//
// History: r1 feature-sharded spmm = +2x fetch (line-granularity) — reverted.
// r2/r5 single-dispatch grid barrier = capture abort / hang risk — parked.
// r4/r6 GPU-acquisition timeouts — no signal; this is the r5 kernel resubmitted.

constexpr int N_NODES = 50000;
constexpr int N_EDGES = 1600000;
constexpr int FEAT    = 128;

constexpr int ROWS_PER_BIN = 64;                                   // bin = row >> 6
constexpr int NB           = (N_NODES + ROWS_PER_BIN - 1) / ROWS_PER_BIN;  // 782
constexpr int CAP          = 2560;   // mean 2046, sd ~45 -> 11 sigma headroom
constexpr int CHUNK        = 4096;   // edges per partition block
constexpr int EPT          = 4;      // edges per thread (1024 thr)
constexpr int PART_BLOCKS  = (N_EDGES + CHUNK - 1) / CHUNK;        // 391
constexpr int GEMM_BLOCKS  = (N_NODES + 255) / 256;                // 196
constexpr int FUSED_GROUPS = 196;    // groups of 3: {part, part, gemm}
constexpr int FUSED_BLOCKS = FUSED_GROUPS * 3;                     // 588
constexpr int OVF_CAP      = 8192;

// MFMA gemm LDS pitch (bf16 elems)
constexpr int PITCH = 136;

typedef short short8 __attribute__((ext_vector_type(8)));
typedef float f32x4  __attribute__((ext_vector_type(4)));
typedef float f32x2  __attribute__((ext_vector_type(2)));

__device__ __forceinline__ unsigned short f2bf(float x) {
    unsigned u = __float_as_uint(x);
    u += 0x7fffu + ((u >> 16) & 1u);   // round to nearest even
    return (unsigned short)(u >> 16);
}
__device__ __forceinline__ float bf2f(unsigned short s) {
    return __uint_as_float(((unsigned)s) << 16);
}

// binbuf entry: (rl:6 [26:31] | col:16 [10:25] | valq:10 [0:9])
__device__ __forceinline__ float dec_val10(unsigned w) {
    return (float)(w & 1023u) * (1.0f / 1023.0f);
}

// ---------------------------------------------------------------------------
// GEMM body (1024 thr): Hb = bf16(X @ W^T) for rows [g*256, g*256+256).
// W staged once (fp32->bf16 LDS, 34.8KB); X fragments global->register.
// A = W-frag (M = H-cols), B = X-frag (N = H-rows); lane holds 4 consecutive
// H-cols -> packed ushort4 stores.
// ---------------------------------------------------------------------------
__device__ void gemm_body(const float* __restrict__ X, const float* __restrict__ W,
                          unsigned short* __restrict__ Hb, int g,
                          unsigned short* Wsh) {
    const int tid  = threadIdx.x;
    const int row0 = g * 256;

    // stage full W: 128x128 fp32 -> bf16 (4 float4 per thread)
#pragma unroll
    for (int t = 0; t < 4; t++) {
        int idx = tid + 1024 * t;          // 4096 float4 total
        int r   = idx >> 5;
        int c4  = (idx & 31) << 2;
        const float4 v = *(const float4*)&W[r * FEAT + c4];
        unsigned lo = f2bf(v.x) | ((unsigned)f2bf(v.y) << 16);
        unsigned hi = f2bf(v.z) | ((unsigned)f2bf(v.w) << 16);
        *(uint2*)&Wsh[r * PITCH + c4] = make_uint2(lo, hi);
    }
    __syncthreads();

    const int w    = tid >> 6;             // 16 waves; wave w -> rows 16w..16w+16
    const int lane = tid & 63;
    const int n    = lane & 15;
    const int q    = lane >> 4;

    f32x4 acc[8];
#pragma unroll
    for (int t = 0; t < 8; t++) acc[t] = (f32x4){0.f, 0.f, 0.f, 0.f};

    int xrow = row0 + 16 * w + n;
    if (xrow >= N_NODES) xrow = N_NODES - 1;   // dup row; store is guarded
    const float* xp = X + (size_t)xrow * FEAT;

#pragma unroll
    for (int kt = 0; kt < 4; kt++) {
        const int ko = kt * 32 + q * 8;
        const float4 a0 = *(const float4*)&xp[ko];
        const float4 a1 = *(const float4*)&xp[ko + 4];
        short8 bfrag;
        bfrag[0] = (short)f2bf(a0.x); bfrag[1] = (short)f2bf(a0.y);
        bfrag[2] = (short)f2bf(a0.z); bfrag[3] = (short)f2bf(a0.w);
        bfrag[4] = (short)f2bf(a1.x); bfrag[5] = (short)f2bf(a1.y);
        bfrag[6] = (short)f2bf(a1.z); bfrag[7] = (short)f2bf(a1.w);
#pragma unroll
        for (int t = 0; t < 8; t++) {
            const short8 afrag = *(const short8*)&Wsh[(16 * t + n) * PITCH + ko];
            acc[t] = __builtin_amdgcn_mfma_f32_16x16x32_bf16(afrag, bfrag, acc[t], 0, 0, 0);
        }
    }

    const int grow = row0 + 16 * w + n;
    if (grow < N_NODES) {
#pragma unroll
        for (int t = 0; t < 8; t++) {
            ushort4 pk;
            pk.x = f2bf(acc[t][0]); pk.y = f2bf(acc[t][1]);
            pk.z = f2bf(acc[t][2]); pk.w = f2bf(acc[t][3]);
            *(ushort4*)&Hb[grow * FEAT + 16 * t + 4 * q] = pk;   // 8B packed
        }
    }
}

// ---------------------------------------------------------------------------
// Partition body (1024 thr): edges [g*CHUNK, ..) -> 64-row bins, 4B entries.
// Counting pass caches (row, word, rank) in regs; one global atomic per
// (block,bin); placement writes block-consecutive runs (~5.2 entries).
// ---------------------------------------------------------------------------
__device__ void partition_body(const int* __restrict__ rows, const int* __restrict__ cols,
                               const float* __restrict__ vals,
                               int* __restrict__ gcur, unsigned* __restrict__ binbuf,
                               int* __restrict__ ovf_cnt, int* __restrict__ ovf,
                               int g, int* smem) {
    int* hist  = smem;        // NB
    int* wbase = smem + NB;   // NB
    const int tid = threadIdx.x;
    const int e0  = g * CHUNK;

    for (int i = tid; i < NB; i += 1024) hist[i] = 0;
    __syncthreads();

    int      myrow[EPT], myrank[EPT];
    unsigned myword[EPT];
#pragma unroll
    for (int t = 0; t < EPT; t++) {
        int e = e0 + t * 1024 + tid;
        if (e < N_EDGES) {
            int r = rows[e];
            unsigned vq = (unsigned)__float2int_rn(vals[e] * 1023.0f);
            myrow[t]  = r;
            myword[t] = ((unsigned)(r & 63) << 26) | ((unsigned)cols[e] << 10) | vq;
            myrank[t] = atomicAdd(&hist[r >> 6], 1);
        } else {
            myrow[t] = -1; myword[t] = 0; myrank[t] = 0;
        }
    }
    __syncthreads();

    for (int i = tid; i < NB; i += 1024) {
        int c = hist[i];
        wbase[i] = (c > 0) ? atomicAdd(&gcur[i], c) : 0;
    }
    __syncthreads();

#pragma unroll
    for (int t = 0; t < EPT; t++) {
        int r = myrow[t];
        if (r < 0) continue;
        int b    = r >> 6;
        int rank = wbase[b] + myrank[t];
        if (rank < CAP) {
            binbuf[(size_t)b * CAP + rank] = myword[t];
        } else {
            int k = atomicAdd(ovf_cnt, 1);
            if (k < OVF_CAP) ovf[k] = e0 + t * 1024 + tid;
        }
    }
}

// Fused: group of 3 blocks -> {partition, partition, gemm}. Both kinds are
// co-resident from the first dispatch wave; MFMA-bound gemm overlaps
// latency-bound partition.
__global__ __launch_bounds__(1024) void gemm_partition(
    const float* __restrict__ X, const float* __restrict__ W,
    unsigned short* __restrict__ Hb,
    const int* __restrict__ rows, const int* __restrict__ cols,
    const float* __restrict__ vals,
    int* __restrict__ gcur, unsigned* __restrict__ binbuf,
    int* __restrict__ ovf_cnt, int* __restrict__ ovf) {
    __shared__ unsigned short Wsh[128 * PITCH];   // 34.8KB; partition uses 6.3KB of it
    const int grp = blockIdx.x / 3;
    const int rem = blockIdx.x - grp * 3;
    if (rem == 2) {
        gemm_body(X, W, Hb, grp, Wsh);
    } else {
        int pg = grp * 2 + rem;
        if (pg < PART_BLOCKS)
            partition_body(rows, cols, vals, gcur, binbuf, ovf_cnt, ovf, pg, (int*)Wsh);
    }
}

// ---------------------------------------------------------------------------
// Binned SpMM: one 512-thr block per 64-row bin. Count from global (L2-hot),
// 64-lane scan, scatter from global into LDS repacked as (bf16val:16|col:16);
// wave w accumulates rows [w*8, w*8+8) in registers (float2/lane), 16-deep
// unrolled bf16 gathers, 2-op decode. In-register overflow fixup (expected
// empty). Nontemporal out stores (write-once data; keep Hb hot in L2).
// ---------------------------------------------------------------------------
__global__ __launch_bounds__(512) void spmm_bins(
    const int* __restrict__ gcur, const unsigned* __restrict__ binbuf,
    const unsigned short* __restrict__ Hb, float* __restrict__ out,
    const int* __restrict__ rows, const int* __restrict__ cols,
    const float* __restrict__ vals,
    const int* __restrict__ ovf_cnt, const int* __restrict__ ovf) {
    __shared__ unsigned sorted[CAP];          // 10.24KB
    __shared__ int hist[ROWS_PER_BIN];
    __shared__ int cnt_of[ROWS_PER_BIN];
    __shared__ int cur[ROWS_PER_BIN];

    const int b    = blockIdx.x;
    const int tid  = threadIdx.x;
    const int lane = tid & 63;
    const int w    = tid >> 6;                // 8 waves

    if (tid < ROWS_PER_BIN) { hist[tid] = 0; cur[tid] = 0; }
    __syncthreads();

    int cnt = gcur[b];
    if (cnt > CAP) cnt = CAP;
    const unsigned* bb = binbuf + (size_t)b * CAP;

    // pass 1: count per row
    for (int i = tid; i < cnt; i += 512)
        atomicAdd(&hist[bb[i] >> 26], 1);
    __syncthreads();

    // exclusive scan of 64 counts (wave 0)
    if (w == 0) {
        int c = hist[lane];
        cnt_of[lane] = c;
        int v = c;
#pragma unroll
        for (int off = 1; off < 64; off <<= 1) {
            int u = __shfl_up(v, off);
            if (lane >= off) v += u;
        }
        hist[lane] = v - c;   // exclusive start
    }
    __syncthreads();

    // pass 2: scatter into row-sorted LDS, repacking to (bf16val:16 | col:16)
    for (int i = tid; i < cnt; i += 512) {
        unsigned m = bb[i];                   // L2-hot re-read
        int rl  = (int)(m >> 26);
        int pos = hist[rl] + atomicAdd(&cur[rl], 1);
        unsigned col = (m >> 10) & 0xffffu;
        unsigned vb  = (unsigned)f2bf(dec_val10(m));
        sorted[pos] = (vb << 16) | col;
    }
    __syncthreads();

    // register accumulation; wave w owns rows [w*8, w*8+8)
    const int row0 = b * ROWS_PER_BIN;
    const ushort2* __restrict__ Hb2 = (const ushort2*)Hb;
    float2* out2 = (float2*)out;

    int novf = *ovf_cnt;                      // expected 0
    if (novf > OVF_CAP) novf = OVF_CAP;

    for (int rr = 0; rr < 8; rr++) {
        const int rl = w * 8 + rr;
        const int gr = row0 + rl;
        if (gr >= N_NODES) break;
        const int s = hist[rl];
        const int e = s + cnt_of[rl];

        float accx = 0.f, accy = 0.f;
        int i = s;
        for (; i + 16 <= e; i += 16) {
            float v[16];
            ushort2 h[16];
#pragma unroll
            for (int j = 0; j < 16; j++) {
                unsigned m = sorted[i + j];                  // wave-uniform broadcast
                int col = (int)(m & 0xffffu);
                v[j] = __uint_as_float(m & 0xffff0000u);     // bf16 val, 1 op
                h[j] = Hb2[col * 64 + lane];                 // 4B/lane, 256B/wave
            }
#pragma unroll
            for (int j = 0; j < 16; j++) {
                accx += v[j] * bf2f(h[j].x);
                accy += v[j] * bf2f(h[j].y);
            }
        }
        for (; i + 4 <= e; i += 4) {
            float v[4];
            ushort2 h[4];
#pragma unroll
            for (int j = 0; j < 4; j++) {
                unsigned m = sorted[i + j];
                int col = (int)(m & 0xffffu);
                v[j] = __uint_as_float(m & 0xffff0000u);
                h[j] = Hb2[col * 64 + lane];
            }
#pragma unroll
            for (int j = 0; j < 4; j++) {
                accx += v[j] * bf2f(h[j].x);
                accy += v[j] * bf2f(h[j].y);
            }
        }
        for (; i < e; i++) {
            unsigned m = sorted[i];
            int col = (int)(m & 0xffffu);
            float vv = __uint_as_float(m & 0xffff0000u);
            ushort2 hh = Hb2[col * 64 + lane];
            accx += vv * bf2f(hh.x);
            accy += vv * bf2f(hh.y);
        }
        // in-register overflow fixup (novf expected 0; exact-correctness net,
        // full precision — replaces the separate fixup_ovf dispatch)
        for (int k = 0; k < novf; k++) {
            int e2 = ovf[k];
            if (rows[e2] == gr) {
                float vv = vals[e2];
                ushort2 hh = Hb2[cols[e2] * 64 + lane];
                accx += vv * bf2f(hh.x);
                accy += vv * bf2f(hh.y);
            }
        }
        f32x2 r; r[0] = accx; r[1] = accy;
        __builtin_nontemporal_store(r, (f32x2*)&out2[(size_t)gr * 64 + lane]);
    }
}

// Fallback (tiny ws): gemm-only + push with global atomics.
__global__ __launch_bounds__(1024) void gemm_only(
    const float* __restrict__ X, const float* __restrict__ W,
    unsigned short* __restrict__ Hb) {
    __shared__ unsigned short Wsh[128 * PITCH];
    gemm_body(X, W, Hb, blockIdx.x, Wsh);
}

__global__ __launch_bounds__(256) void spmm_push_atomic(
    const int* __restrict__ rows, const int* __restrict__ cols,
    const float* __restrict__ vals, const unsigned short* __restrict__ Hb,
    float* __restrict__ out) {
    const int e    = blockIdx.x * 4 + (threadIdx.x >> 6);
    const int lane = threadIdx.x & 63;
    if (e >= N_EDGES) return;
    int r = rows[e], c = cols[e];
    float v = vals[e];
    atomicAdd(&out[r * FEAT + lane],      v * bf2f(Hb[c * FEAT + lane]));
    atomicAdd(&out[r * FEAT + 64 + lane], v * bf2f(Hb[c * FEAT + 64 + lane]));
}

// ---------------------------------------------------------------------------
extern "C" void kernel_launch(void* const* d_in, const int* in_sizes, int n_in,
                              void* d_out, int out_size, void* d_ws, size_t ws_size,
                              hipStream_t stream) {
    const float* X      = (const float*)d_in[0];
    const float* W      = (const float*)d_in[1];
    const float* A_vals = (const float*)d_in[2];
    const int*   A_rows = (const int*)d_in[3];
    const int*   A_cols = (const int*)d_in[4];
    float* out = (float*)d_out;

    auto align256 = [](size_t x) { return (x + 255) & ~size_t(255); };
    char* ws = (char*)d_ws;

    size_t off = 0;
    size_t hb_off   = off; off += align256(size_t(N_NODES) * FEAT * 2);        // 12.8MB
    size_t gcur_off = off; off += align256(size_t(NB) * sizeof(int));
    size_t ovfc_off = off; off += 256;
    size_t ovf_off  = off; off += align256(size_t(OVF_CAP) * sizeof(int));
    size_t bin_off  = off; off += size_t(NB) * CAP * sizeof(unsigned);         // 8.0MB
    const size_t need = off;

    unsigned short* Hb = (unsigned short*)(ws + hb_off);

    if (ws_size >= need) {
        int*      gcur    = (int*)(ws + gcur_off);
        int*      ovf_cnt = (int*)(ws + ovfc_off);
        int*      ovf     = (int*)(ws + ovf_off);
        unsigned* binbuf  = (unsigned*)(ws + bin_off);

        // zero gcur + ovf_cnt (contiguous, ~6.6KB) before the fused kernel
        (void)hipMemsetAsync(ws + gcur_off, 0, (ovfc_off - gcur_off) + 256, stream);
        gemm_partition<<<FUSED_BLOCKS, 1024, 0, stream>>>(X, W, Hb, A_rows, A_cols, A_vals,
                                                          gcur, binbuf, ovf_cnt, ovf);
        spmm_bins<<<NB, 512, 0, stream>>>(gcur, binbuf, Hb, out,
                                          A_rows, A_cols, A_vals, ovf_cnt, ovf);
    } else {
        // Safety path: bf16 H + atomic push.
        gemm_only<<<GEMM_BLOCKS, 1024, 0, stream>>>(X, W, Hb);
        (void)hipMemsetAsync(out, 0, size_t(N_NODES) * FEAT * sizeof(float), stream);
        spmm_push_atomic<<<(N_EDGES + 3) / 4, 256, 0, stream>>>(A_rows, A_cols, A_vals, Hb, out);
    }
}

// Round 9
// 164.209 us; speedup vs baseline: 1.1406x; 1.0253x over previous
//
#include <hip/hip_runtime.h>

// GCN layer: H = X @ W^T ; out = A_coo @ H     (N=50000, E=1600000, F=128)
//
// Pipeline (3 graph nodes):
//   memset(6.6KB counters)
//   -> fused 1024-thr kernel: MFMA gemm blocks (256 rows each, W staged once
//      in LDS, X global->reg, QUARTER-MAJOR Hb store) interleaved 1:2 with
//      edge-partition blocks (64-row bins, 4B entries)
//   -> binned SpMM, feature-sharded v2: 4 blocks per bin, quarter q owns
//      feats [32q,32q+32). Hb is quarter-major (Hb[q][node][32], 3.2MB/q)
//      so a quarter's gather set is CONTIGUOUS and fits one 4MB XCD L2;
//      q=(bid&7)>>1 pins each quarter to an XCD pair (r1's failure was
//      row-major layout: 64B sub-line gathers fetched each 128B line twice).
//      Single-pass direct-slot counting sort (64 slots/row, +5.6 sigma;
//      LDS row-overflow net) replaces count+scan+scatter. Register accum
//      (8 waves x 8 rows, 4 edge-slots x 16 lanes), in-register overflow
//      fixups, nontemporal stores.
//
// History: r1 sharding w/ row-major layout = +2x fetch — root-caused, fixed
// here. r2/r5 grid-barrier single dispatch = capture abort/hang — parked.
// r7: fixup fold + NT stores = -3us; dispatch-gap is fixed overhead, so
// this round attacks spmm's L2-miss path (141.7MB @ 2.4TB/s = the limit).
// r8: GPU-acquisition timeout — no signal; identical resubmit.

constexpr int N_NODES = 50000;
constexpr int N_EDGES = 1600000;
constexpr int FEAT    = 128;

constexpr int ROWS_PER_BIN = 64;                                   // bin = row >> 6
constexpr int NB           = (N_NODES + ROWS_PER_BIN - 1) / ROWS_PER_BIN;  // 782
constexpr int CAP          = 2560;   // mean 2046, sd ~45 -> 11 sigma headroom
constexpr int CHUNK        = 4096;   // edges per partition block
constexpr int EPT          = 4;      // edges per thread (1024 thr)
constexpr int PART_BLOCKS  = (N_EDGES + CHUNK - 1) / CHUNK;        // 391
constexpr int GEMM_BLOCKS  = (N_NODES + 255) / 256;                // 196
constexpr int FUSED_GROUPS = 196;    // groups of 3: {part, part, gemm}
constexpr int FUSED_BLOCKS = FUSED_GROUPS * 3;                     // 588
constexpr int OVF_CAP      = 8192;

constexpr int RSLOT    = 64;         // direct slots per row (Poisson(32)+5.6s)
constexpr int ROVF_CAP = 256;        // per-bin row-overflow net

static_assert(NB % 2 == 0, "bin<->block mapping needs even NB");

// MFMA gemm LDS pitch (bf16 elems)
constexpr int PITCH = 136;

typedef short short8 __attribute__((ext_vector_type(8)));
typedef float f32x4  __attribute__((ext_vector_type(4)));
typedef float f32x2  __attribute__((ext_vector_type(2)));

__device__ __forceinline__ unsigned short f2bf(float x) {
    unsigned u = __float_as_uint(x);
    u += 0x7fffu + ((u >> 16) & 1u);   // round to nearest even
    return (unsigned short)(u >> 16);
}
__device__ __forceinline__ float bf2f(unsigned short s) {
    return __uint_as_float(((unsigned)s) << 16);
}

// binbuf entry: (rl:6 [26:31] | col:16 [10:25] | valq:10 [0:9])
__device__ __forceinline__ float dec_val10(unsigned w) {
    return (float)(w & 1023u) * (1.0f / 1023.0f);
}

// ---------------------------------------------------------------------------
// GEMM body (1024 thr): Hb = bf16(X @ W^T), QUARTER-MAJOR: Hb[q][node][32].
// W staged once (fp32->bf16 LDS, 34.8KB); X fragments global->register.
// Lane holds 4 consecutive H-cols (16t+4q..+4) — always within one quarter,
// so the packed ushort4 store stays a single 8B write.
// ---------------------------------------------------------------------------
__device__ void gemm_body(const float* __restrict__ X, const float* __restrict__ W,
                          unsigned short* __restrict__ Hb, int g,
                          unsigned short* Wsh) {
    const int tid  = threadIdx.x;
    const int row0 = g * 256;

    // stage full W: 128x128 fp32 -> bf16 (4 float4 per thread)
#pragma unroll
    for (int t = 0; t < 4; t++) {
        int idx = tid + 1024 * t;          // 4096 float4 total
        int r   = idx >> 5;
        int c4  = (idx & 31) << 2;
        const float4 v = *(const float4*)&W[r * FEAT + c4];
        unsigned lo = f2bf(v.x) | ((unsigned)f2bf(v.y) << 16);
        unsigned hi = f2bf(v.z) | ((unsigned)f2bf(v.w) << 16);
        *(uint2*)&Wsh[r * PITCH + c4] = make_uint2(lo, hi);
    }
    __syncthreads();

    const int w    = tid >> 6;             // 16 waves; wave w -> rows 16w..16w+16
    const int lane = tid & 63;
    const int n    = lane & 15;
    const int q    = lane >> 4;

    f32x4 acc[8];
#pragma unroll
    for (int t = 0; t < 8; t++) acc[t] = (f32x4){0.f, 0.f, 0.f, 0.f};

    int xrow = row0 + 16 * w + n;
    if (xrow >= N_NODES) xrow = N_NODES - 1;   // dup row; store is guarded
    const float* xp = X + (size_t)xrow * FEAT;

#pragma unroll
    for (int kt = 0; kt < 4; kt++) {
        const int ko = kt * 32 + q * 8;
        const float4 a0 = *(const float4*)&xp[ko];
        const float4 a1 = *(const float4*)&xp[ko + 4];
        short8 bfrag;
        bfrag[0] = (short)f2bf(a0.x); bfrag[1] = (short)f2bf(a0.y);
        bfrag[2] = (short)f2bf(a0.z); bfrag[3] = (short)f2bf(a0.w);
        bfrag[4] = (short)f2bf(a1.x); bfrag[5] = (short)f2bf(a1.y);
        bfrag[6] = (short)f2bf(a1.z); bfrag[7] = (short)f2bf(a1.w);
#pragma unroll
        for (int t = 0; t < 8; t++) {
            const short8 afrag = *(const short8*)&Wsh[(16 * t + n) * PITCH + ko];
            acc[t] = __builtin_amdgcn_mfma_f32_16x16x32_bf16(afrag, bfrag, acc[t], 0, 0, 0);
        }
    }

    const int grow = row0 + 16 * w + n;
    if (grow < N_NODES) {
#pragma unroll
        for (int t = 0; t < 8; t++) {
            ushort4 pk;
            pk.x = f2bf(acc[t][0]); pk.y = f2bf(acc[t][1]);
            pk.z = f2bf(acc[t][2]); pk.w = f2bf(acc[t][3]);
            const int col0 = 16 * t + 4 * q;               // cols col0..col0+3
            unsigned short* dst = Hb + ((size_t)(col0 >> 5) * N_NODES + grow) * 32
                                     + (col0 & 31);        // quarter-major
            *(ushort4*)dst = pk;                           // 8B packed
        }
    }
}

// ---------------------------------------------------------------------------
// Partition body (1024 thr): edges [g*CHUNK, ..) -> 64-row bins, 4B entries.
// Counting pass caches (row, word, rank) in regs; one global atomic per
// (block,bin); placement writes block-consecutive runs (~5.2 entries).
// ---------------------------------------------------------------------------
__device__ void partition_body(const int* __restrict__ rows, const int* __restrict__ cols,
                               const float* __restrict__ vals,
                               int* __restrict__ gcur, unsigned* __restrict__ binbuf,
                               int* __restrict__ ovf_cnt, int* __restrict__ ovf,
                               int g, int* smem) {
    int* hist  = smem;        // NB
    int* wbase = smem + NB;   // NB
    const int tid = threadIdx.x;
    const int e0  = g * CHUNK;

    for (int i = tid; i < NB; i += 1024) hist[i] = 0;
    __syncthreads();

    int      myrow[EPT], myrank[EPT];
    unsigned myword[EPT];
#pragma unroll
    for (int t = 0; t < EPT; t++) {
        int e = e0 + t * 1024 + tid;
        if (e < N_EDGES) {
            int r = rows[e];
            unsigned vq = (unsigned)__float2int_rn(vals[e] * 1023.0f);
            myrow[t]  = r;
            myword[t] = ((unsigned)(r & 63) << 26) | ((unsigned)cols[e] << 10) | vq;
            myrank[t] = atomicAdd(&hist[r >> 6], 1);
        } else {
            myrow[t] = -1; myword[t] = 0; myrank[t] = 0;
        }
    }
    __syncthreads();

    for (int i = tid; i < NB; i += 1024) {
        int c = hist[i];
        wbase[i] = (c > 0) ? atomicAdd(&gcur[i], c) : 0;
    }
    __syncthreads();

#pragma unroll
    for (int t = 0; t < EPT; t++) {
        int r = myrow[t];
        if (r < 0) continue;
        int b    = r >> 6;
        int rank = wbase[b] + myrank[t];
        if (rank < CAP) {
            binbuf[(size_t)b * CAP + rank] = myword[t];
        } else {
            int k = atomicAdd(ovf_cnt, 1);
            if (k < OVF_CAP) ovf[k] = e0 + t * 1024 + tid;
        }
    }
}

// Fused: group of 3 blocks -> {partition, partition, gemm}. Both kinds are
// co-resident from the first dispatch wave; MFMA-bound gemm overlaps
// latency-bound partition.
__global__ __launch_bounds__(1024) void gemm_partition(
    const float* __restrict__ X, const float* __restrict__ W,
    unsigned short* __restrict__ Hb,
    const int* __restrict__ rows, const int* __restrict__ cols,
    const float* __restrict__ vals,
    int* __restrict__ gcur, unsigned* __restrict__ binbuf,
    int* __restrict__ ovf_cnt, int* __restrict__ ovf) {
    __shared__ unsigned short Wsh[128 * PITCH];   // 34.8KB; partition uses 6.3KB of it
    const int grp = blockIdx.x / 3;
    const int rem = blockIdx.x - grp * 3;
    if (rem == 2) {
        gemm_body(X, W, Hb, grp, Wsh);
    } else {
        int pg = grp * 2 + rem;
        if (pg < PART_BLOCKS)
            partition_body(rows, cols, vals, gcur, binbuf, ovf_cnt, ovf, pg, (int*)Wsh);
    }
}

// ---------------------------------------------------------------------------
// Binned SpMM, feature-sharded v2 (quarter-major Hb): grid = NB*4 = 391*8.
// xcd = bid&7; q = xcd>>1 (quarter pinned to XCD pair, 3.2MB slice fits 4MB
// L2); b = (bid>>3)*2 + (bid&1). Single-pass direct-slot sort: 64 slots/row,
// overflow to LDS list (expected empty). Per wave: 4 edge-slots x 16 lanes,
// 64B contiguous gather per edge from the hot quarter; shfl_xor 16/32 reduce;
// slot 0 stores 128B/row nontemporal.
// ---------------------------------------------------------------------------
__global__ __launch_bounds__(512) void spmm_bins(
    const int* __restrict__ gcur, const unsigned* __restrict__ binbuf,
    const unsigned short* __restrict__ Hb, float* __restrict__ out,
    const int* __restrict__ rows, const int* __restrict__ cols,
    const float* __restrict__ vals,
    const int* __restrict__ ovf_cnt, const int* __restrict__ ovf) {
    __shared__ unsigned sorted[ROWS_PER_BIN * RSLOT];   // 16KB
    __shared__ int cur[ROWS_PER_BIN];
    __shared__ unsigned rovf[ROVF_CAP];                 // 1KB
    __shared__ int rovf_cnt;

    const int bid  = blockIdx.x;
    const int q    = (bid & 7) >> 1;              // feature quarter (XCD-paired)
    const int b    = (bid >> 3) * 2 + (bid & 1);  // bin index, 0..781
    const int tid  = threadIdx.x;
    const int lane = tid & 63;
    const int w    = tid >> 6;                    // 8 waves

    if (tid < ROWS_PER_BIN) cur[tid] = 0;
    if (tid == ROWS_PER_BIN) rovf_cnt = 0;
    __syncthreads();

    int cnt = gcur[b];
    if (cnt > CAP) cnt = CAP;
    const unsigned* bb = binbuf + (size_t)b * CAP;

    // single pass: direct-slot scatter, repack to (bf16val:16 | col:16)
    for (int i = tid; i < cnt; i += 512) {
        unsigned m   = bb[i];
        int rl       = (int)(m >> 26);
        int pos      = atomicAdd(&cur[rl], 1);
        unsigned col = (m >> 10) & 0xffffu;
        unsigned vb  = (unsigned)f2bf(dec_val10(m));
        if (pos < RSLOT) {
            sorted[rl * RSLOT + pos] = (vb << 16) | col;
        } else {
            int k = atomicAdd(&rovf_cnt, 1);
            if (k < ROVF_CAP) rovf[k] = m;
        }
    }
    __syncthreads();

    int nrovf = rovf_cnt;
    if (nrovf > ROVF_CAP) nrovf = ROVF_CAP;
    int novf = *ovf_cnt;                          // expected 0
    if (novf > OVF_CAP) novf = OVF_CAP;

    // register accumulation; wave w owns rows [w*8, w*8+8)
    const int row0   = b * ROWS_PER_BIN;
    const int slot   = lane >> 4;                 // 0..3, one edge per slot
    const int lane16 = lane & 15;                 // 2 feats (ushort2) per lane
    const ushort2* __restrict__ Hq2 = (const ushort2*)(Hb + (size_t)q * N_NODES * 32);
    float2* out2 = (float2*)out;

    for (int rr = 0; rr < 8; rr++) {
        const int rl = w * 8 + rr;
        const int gr = row0 + rl;
        if (gr >= N_NODES) break;
        int e = cur[rl];
        if (e > RSLOT) e = RSLOT;
        const unsigned* srow = &sorted[rl * RSLOT];

        float accx = 0.f, accy = 0.f;
        int i = 0;
        for (; i + 16 <= e; i += 16) {            // 16 edges = 4 steps x 4 slots
            float   vv[4];
            ushort2 hh[4];
#pragma unroll
            for (int u = 0; u < 4; u++) {
                unsigned m = srow[i + u * 4 + slot];        // 4-way LDS broadcast
                vv[u] = __uint_as_float(m & 0xffff0000u);
                hh[u] = Hq2[(int)(m & 0xffffu) * 16 + lane16];  // 64B/edge, L2-hot
            }
#pragma unroll
            for (int u = 0; u < 4; u++) {
                accx += vv[u] * bf2f(hh[u].x);
                accy += vv[u] * bf2f(hh[u].y);
            }
        }
        for (; i < e; i += 4) {                   // masked 4-at-a-time tail
            int idx = i + slot;
            unsigned m = (idx < e) ? srow[idx] : 0u;        // m=0 -> v=0
            float v2 = __uint_as_float(m & 0xffff0000u);
            ushort2 h2 = Hq2[(int)(m & 0xffffu) * 16 + lane16];
            accx += v2 * bf2f(h2.x);
            accy += v2 * bf2f(h2.y);
        }
        // row-slot overflow net (expected empty); slot 0 only (summed once)
        for (int k = 0; k < nrovf; k++) {
            unsigned m = rovf[k];
            if ((int)(m >> 26) == rl && slot == 0) {
                float vv = dec_val10(m);
                ushort2 h2 = Hq2[(int)((m >> 10) & 0xffffu) * 16 + lane16];
                accx += vv * bf2f(h2.x);
                accy += vv * bf2f(h2.y);
            }
        }
        // bin-capacity overflow net (expected empty); full precision
        for (int k = 0; k < novf; k++) {
            int e2 = ovf[k];
            if (rows[e2] == gr && slot == 0) {
                float vv = vals[e2];
                ushort2 h2 = Hq2[cols[e2] * 16 + lane16];
                accx += vv * bf2f(h2.x);
                accy += vv * bf2f(h2.y);
            }
        }
        // reduce across the 4 edge-slots
        accx += __shfl_xor(accx, 16); accy += __shfl_xor(accy, 16);
        accx += __shfl_xor(accx, 32); accy += __shfl_xor(accy, 32);
        if (slot == 0) {
            f32x2 r; r[0] = accx; r[1] = accy;
            __builtin_nontemporal_store(r, (f32x2*)&out2[(size_t)gr * 64 + q * 16 + lane16]);
        }
    }
}

// Fallback (tiny ws): gemm-only + push with global atomics (quarter-major Hb).
__global__ __launch_bounds__(1024) void gemm_only(
    const float* __restrict__ X, const float* __restrict__ W,
    unsigned short* __restrict__ Hb) {
    __shared__ unsigned short Wsh[128 * PITCH];
    gemm_body(X, W, Hb, blockIdx.x, Wsh);
}

__global__ __launch_bounds__(256) void spmm_push_atomic(
    const int* __restrict__ rows, const int* __restrict__ cols,
    const float* __restrict__ vals, const unsigned short* __restrict__ Hb,
    float* __restrict__ out) {
    const int e    = blockIdx.x * 4 + (threadIdx.x >> 6);
    const int lane = threadIdx.x & 63;
    if (e >= N_EDGES) return;
    int r = rows[e], c = cols[e];
    float v = vals[e];
    const int f1 = lane, f2 = lane + 64;
    float h1 = bf2f(Hb[((size_t)(f1 >> 5) * N_NODES + c) * 32 + (f1 & 31)]);
    float h2 = bf2f(Hb[((size_t)(f2 >> 5) * N_NODES + c) * 32 + (f2 & 31)]);
    atomicAdd(&out[r * FEAT + f1], v * h1);
    atomicAdd(&out[r * FEAT + f2], v * h2);
}

// ---------------------------------------------------------------------------
extern "C" void kernel_launch(void* const* d_in, const int* in_sizes, int n_in,
                              void* d_out, int out_size, void* d_ws, size_t ws_size,
                              hipStream_t stream) {
    const float* X      = (const float*)d_in[0];
    const float* W      = (const float*)d_in[1];
    const float* A_vals = (const float*)d_in[2];
    const int*   A_rows = (const int*)d_in[3];
    const int*   A_cols = (const int*)d_in[4];
    float* out = (float*)d_out;

    auto align256 = [](size_t x) { return (x + 255) & ~size_t(255); };
    char* ws = (char*)d_ws;

    size_t off = 0;
    size_t hb_off   = off; off += align256(size_t(N_NODES) * FEAT * 2);        // 12.8MB
    size_t gcur_off = off; off += align256(size_t(NB) * sizeof(int));
    size_t ovfc_off = off; off += 256;
    size_t ovf_off  = off; off += align256(size_t(OVF_CAP) * sizeof(int));
    size_t bin_off  = off; off += size_t(NB) * CAP * sizeof(unsigned);         // 8.0MB
    const size_t need = off;

    unsigned short* Hb = (unsigned short*)(ws + hb_off);

    if (ws_size >= need) {
        int*      gcur    = (int*)(ws + gcur_off);
        int*      ovf_cnt = (int*)(ws + ovfc_off);
        int*      ovf     = (int*)(ws + ovf_off);
        unsigned* binbuf  = (unsigned*)(ws + bin_off);

        // zero gcur + ovf_cnt (contiguous, ~6.6KB) before the fused kernel
        (void)hipMemsetAsync(ws + gcur_off, 0, (ovfc_off - gcur_off) + 256, stream);
        gemm_partition<<<FUSED_BLOCKS, 1024, 0, stream>>>(X, W, Hb, A_rows, A_cols, A_vals,
                                                          gcur, binbuf, ovf_cnt, ovf);
        spmm_bins<<<NB * 4, 512, 0, stream>>>(gcur, binbuf, Hb, out,
                                              A_rows, A_cols, A_vals, ovf_cnt, ovf);
    } else {
        // Safety path: bf16 H + atomic push.
        gemm_only<<<GEMM_BLOCKS, 1024, 0, stream>>>(X, W, Hb);
        (void)hipMemsetAsync(out, 0, size_t(N_NODES) * FEAT * sizeof(float), stream);
        spmm_push_atomic<<<(N_EDGES + 3) / 4, 256, 0, stream>>>(A_rows, A_cols, A_vals, Hb, out);
    }
}